// Round 9
// baseline (309.668 us; speedup 1.0000x reference)
//
#include <hip/hip_runtime.h>
#include <hip/hip_bf16.h>

typedef unsigned short u16;
typedef short short8 __attribute__((ext_vector_type(8)));
typedef short bf16x4 __attribute__((ext_vector_type(4)));
typedef float f32x4 __attribute__((ext_vector_type(4)));
typedef float f32x16 __attribute__((ext_vector_type(16)));

#define B_SZ 4
#define T_SEQ 2048
#define DMODEL 1024
#define NH 16
#define HD 64
#define QKV_ELEMS 8388608ull  // B*NH*T*HD
#define QSCALE (0.125f * 1.44269504f)   // HD^-0.5 * log2(e), folded into Q

__device__ __forceinline__ u16 f2bf(float f) {
    __hip_bfloat16 h = __float2bfloat16(f);
    return __builtin_bit_cast(u16, h);
}

// async global->LDS, 16B/lane; lane i lands at base + 16*i (wave-uniform base).
__device__ __forceinline__ void gload16(const void* g, void* l) {
    __builtin_amdgcn_global_load_lds(
        (const __attribute__((address_space(1))) unsigned int*)g,
        (__attribute__((address_space(3))) unsigned int*)l, 16, 0, 0);
}

// ---------------------------------------------------------------------------
// Fused prep (R8, verified -29 us vs serial launches): one launch replaces
// cast_x + 2 tcasts. Blocks [0,2048): cast x -> bf16, 4x float4/thread.
// Blocks [2048,2240): transpose-cast w_qkv. [2240,2304): w_proj.
// ---------------------------------------------------------------------------
#define NCX 2048
__global__ __launch_bounds__(256) void prep_kernel(
    const float4* __restrict__ x, u16* __restrict__ xb,
    const float* __restrict__ w_qkv, u16* __restrict__ wqT,
    const float* __restrict__ w_proj, u16* __restrict__ wpT)
{
    const int b = blockIdx.x;
    if (b < NCX) {
        int i = b * 256 + threadIdx.x;
#pragma unroll
        for (int rep = 0; rep < 4; ++rep, i += NCX * 256) {
            const float4 v = x[i];
            union { u16 u[4]; uint2 d; } p;
            p.u[0] = f2bf(v.x); p.u[1] = f2bf(v.y);
            p.u[2] = f2bf(v.z); p.u[3] = f2bf(v.w);
            *(uint2*)(xb + (size_t)i * 4) = p.d;
        }
    } else if (b < NCX + 192) {
        const int bb2 = b - NCX;
        const int n = (bb2 % 12) * 256 + threadIdx.x;
        const int k0 = (bb2 / 12) * 64;
        for (int kk = 0; kk < 64; kk += 8) {
            short8 o;
#pragma unroll
            for (int e = 0; e < 8; ++e)
                o[e] = (short)f2bf(w_qkv[(size_t)(k0 + kk + e) * 3072 + n]);
            *(short8*)&wqT[(size_t)n * 1024 + k0 + kk] = o;
        }
    } else {
        const int bb2 = b - NCX - 192;
        const int n = (bb2 % 4) * 256 + threadIdx.x;
        const int k0 = (bb2 / 4) * 64;
        for (int kk = 0; kk < 64; kk += 8) {
            short8 o;
#pragma unroll
            for (int e = 0; e < 8; ++e)
                o[e] = (short)f2bf(w_proj[(size_t)(k0 + kk + e) * 1024 + n]);
            *(short8*)&wpT[(size_t)n * 1024 + k0 + kk] = o;
        }
    }
}

// ---------------------------------------------------------------------------
// bf16 MFMA GEMM 128x128xBK64 — EXACT R3/R8 state (verified; splits/swaps
// regressed). EPI=0: scatter q (pre-scaled) / k into [B,H,T,HD] and V
// TRANSPOSED into [B,H,HD,T]. EPI=1: fp32 out.
// ---------------------------------------------------------------------------
template <int EPI>
__global__ __launch_bounds__(256) void gemm_kernel(
    const u16* __restrict__ A, const u16* __restrict__ Bt,
    const float* __restrict__ bias, void* __restrict__ outp)
{
    __shared__ u16 As[128 * 64];
    __shared__ u16 Bs[128 * 64];
    const int tid = threadIdx.x;
    const int l = tid & 63;
    const int w = tid >> 6;
    const int wm = w >> 1, wn = w & 1;
    const int m0 = blockIdx.y * 128, n0 = blockIdx.x * 128;
    const int srow = l >> 3;
    const int sch  = (l & 7) ^ srow;
    const int fr = l & 15, fq = l >> 4;

    f32x4 acc[4][4] = {};

    for (int k0 = 0; k0 < 1024; k0 += 64) {
        __syncthreads();
#pragma unroll
        for (int ii = 0; ii < 4; ++ii) {
            const int row = w * 32 + ii * 8;
            gload16(&A[(size_t)(m0 + row + srow) * 1024 + k0 + sch * 8], &As[row * 64]);
            gload16(&Bt[(size_t)(n0 + row + srow) * 1024 + k0 + sch * 8], &Bs[row * 64]);
        }
        __syncthreads();
#pragma unroll
        for (int ks = 0; ks < 2; ++ks) {
            short8 af[4], bf[4];
#pragma unroll
            for (int t = 0; t < 4; ++t) {
                const int ar = wm * 64 + t * 16 + fr;
                af[t] = *(const short8*)&As[ar * 64 + (((ks * 4 + fq) ^ (l & 7)) << 3)];
                const int br = wn * 64 + t * 16 + fr;
                bf[t] = *(const short8*)&Bs[br * 64 + (((ks * 4 + fq) ^ (l & 7)) << 3)];
            }
#pragma unroll
            for (int mt = 0; mt < 4; ++mt)
#pragma unroll
                for (int nt = 0; nt < 4; ++nt)
                    acc[mt][nt] = __builtin_amdgcn_mfma_f32_16x16x32_bf16(
                        af[mt], bf[nt], acc[mt][nt], 0, 0, 0);
        }
    }

    if (EPI == 0) {
        u16* qkv = (u16*)outp;
#pragma unroll
        for (int nt = 0; nt < 4; ++nt) {
            const int n = n0 + wn * 64 + nt * 16 + fr;
            const float bs = bias[n];
            const int which = n >> 10, hh = (n >> 6) & 15, d = n & 63;
            if (which == 2) {
                // V transposed: [b][h][d][t]; lane's 4 r-values are t-contiguous
                u16* dst = qkv + 2 * QKV_ELEMS;
#pragma unroll
                for (int mt = 0; mt < 4; ++mt) {
                    const int m = m0 + wm * 64 + mt * 16 + fq * 4;
                    const int bb = m >> 11, t = m & 2047;
                    bf16x4 ov;
#pragma unroll
                    for (int r = 0; r < 4; ++r) ov[r] = (short)f2bf(acc[mt][nt][r] + bs);
                    *(bf16x4*)&dst[(((size_t)(bb * NH + hh)) * HD + d) * T_SEQ + t] = ov;
                }
            } else {
                const float scl = (which == 0) ? QSCALE : 1.0f;
                u16* dst = qkv + (size_t)which * QKV_ELEMS + (size_t)hh * T_SEQ * HD + d;
#pragma unroll
                for (int mt = 0; mt < 4; ++mt)
#pragma unroll
                    for (int r = 0; r < 4; ++r) {
                        const int m = m0 + wm * 64 + mt * 16 + fq * 4 + r;
                        const int bb = m >> 11, t = m & 2047;
                        dst[(size_t)bb * (NH * T_SEQ * HD) + (size_t)t * HD] =
                            f2bf((acc[mt][nt][r] + bs) * scl);
                    }
            }
        }
    } else {
        float* C = (float*)outp;
#pragma unroll
        for (int nt = 0; nt < 4; ++nt) {
            const int n = n0 + wn * 64 + nt * 16 + fr;
            const float bs = bias[n];
#pragma unroll
            for (int mt = 0; mt < 4; ++mt)
#pragma unroll
                for (int r = 0; r < 4; ++r) {
                    const int m = m0 + wm * 64 + mt * 16 + fq * 4 + r;
                    C[(size_t)m * DMODEL + n] = acc[mt][nt][r] + bs;
                }
        }
    }
}

// ---------------------------------------------------------------------------
// MFMA flash attention — R8 structure with KVBLK=128 (was 64). The pair
// (qi, 15-qi) at 128-wide kv tiles = (qi+1)+(16-qi) = EXACTLY 17 rounds per
// block (uniformity automatic), halving the 34 per-round fixed costs
// (barrier + vmcnt drain + staging-issue serialization) that dominate at
// ~7000 cyc/round. LDS 64 KB -> still 2 blocks/CU. Stream order, 8-heads-
// per-XCD L2 pinning, fixed-shift softmax, setprio all unchanged.
// Per round: two 64-wide compute passes reuse st[2] (VGPR unchanged).
// V LDS row = 256 B; swizzle = XOR (d&15) over 16 chunks of 16 B, applied
// on pre-swizzled global source AND read (both-sides rule); reads <=2-way.
// ---------------------------------------------------------------------------
__global__ __launch_bounds__(256) void attn_kernel(
    const u16* __restrict__ q, const u16* __restrict__ k,
    const u16* __restrict__ vT, u16* __restrict__ y)
{
    __shared__ u16 Ks[2][128 * 64];   // 16 KB each: [j][d], 128-row kv tile
    __shared__ u16 Vs[2][64 * 128];   // 16 KB each: [d][t], 128-col kv tile

    int flat = blockIdx.x;
    flat = (flat & 7) * 64 + (flat >> 3);
    const int qip = flat & 7;
    const int hh = (flat >> 3) & 15;
    const int bb = flat >> 7;

    const size_t hbase = ((size_t)(bb * NH + hh)) * T_SEQ * HD;
    const u16* qb = q + hbase;
    const u16* kb = k + hbase;
    const u16* vTb = vT + hbase;     // [d][t]

    const int tid = threadIdx.x;
    const int l = tid & 63;
    const int w = tid >> 6;
    const int qn = l & 31;           // q within wave tile
    const int h = l >> 5;            // half-wave
    const int srow = l >> 3;         // K/Q staging: lane row within 8 (128B rows)
    const int sch = (l & 7) ^ srow;  // K/Q staging source chunk (XOR swizzle)
    const int vrow = l >> 4;         // V staging: lane row within 4 (256B rows)
    const int vch = l & 15;          // V staging LDS chunk

    u16* Qstage = &Ks[0][0];         // 16 KB = exactly buffer 0

    for (int pp = 0; pp < 2; ++pp) {
        const int qi = pp ? (15 - qip) : qip;
        const int q0 = qi * 128;

        __syncthreads();   // previous tile fully done with LDS

        // stage Q (128 rows -> Ks[0]) + V tile 0
#pragma unroll
        for (int ii = 0; ii < 4; ++ii) {
            const int row = w * 32 + ii * 8;
            gload16(&qb[(size_t)(q0 + row + srow) * HD + sch * 8], &Qstage[row * 64]);
        }
#pragma unroll
        for (int ii = 0; ii < 4; ++ii) {
            const int d = w * 16 + ii * 4 + vrow;
            gload16(&vTb[(size_t)d * T_SEQ + ((vch ^ (d & 15)) << 3)],
                    &Vs[0][(w * 16 + ii * 4) * 128]);
        }
        __syncthreads();   // Q + V0 landed

        // hoist Q fragments (B-operand 32x32x16: n=q=qn, k=k16*16+h*8+e)
        short8 qf[4];
        {
            const int qrow = w * 32 + qn;
#pragma unroll
            for (int k16 = 0; k16 < 4; ++k16)
                qf[k16] = *(const short8*)
                    &Qstage[qrow * 64 + (((k16 * 2 + h) ^ (qrow & 7)) << 3)];
        }
        __syncthreads();   // all waves done reading Q; Ks[0] reusable

        // K tile 0 (128 rows)
#pragma unroll
        for (int ii = 0; ii < 4; ++ii) {
            const int row = w * 32 + ii * 8;
            gload16(&kb[(size_t)(row + srow) * HD + sch * 8], &Ks[0][row * 64]);
        }

        const int q0w = q0 + w * 32;     // this wave's first q row
        float l_run = 0.f;
        f32x16 o_acc[2] = {};            // O^T: d=dt*32+(r&3)+8(r>>2)+4h, col=qn

        const int nkt = qi + 1;          // 128-wide rounds
        for (int kt = 0; kt < nkt; ++kt) {
            __syncthreads();   // drains prev gloads (incl. tile 0) + readers done
            if (kt + 1 < nkt) {
                const int nb = (kt + 1) & 1;
                const int jj = (kt + 1) * 128;
#pragma unroll
                for (int ii = 0; ii < 4; ++ii) {
                    const int row = w * 32 + ii * 8;
                    gload16(&kb[(size_t)(jj + row + srow) * HD + sch * 8],
                            &Ks[nb][row * 64]);
                }
#pragma unroll
                for (int ii = 0; ii < 4; ++ii) {
                    const int d = w * 16 + ii * 4 + vrow;
                    gload16(&vTb[(size_t)d * T_SEQ + jj + ((vch ^ (d & 15)) << 3)],
                            &Vs[nb][(w * 16 + ii * 4) * 128]);
                }
            }
            const int buf = kt & 1;
            const int j0 = kt * 128;

            if (j0 > q0w + 31) continue;      // whole round masked for this wave

            // two 64-wide passes over the staged 128-col tile (st[2] reused)
#pragma unroll
            for (int p2 = 0; p2 < 2; ++p2) {
                const int jb = j0 + p2 * 64;
                if (jb > q0w + 31) break;     // second pass masked
                const int njt = (jb + 32 <= q0w + 31) ? 2 : 1;

                // S^T = K Q^T, accumulator pre-shifted by -16 (softmax shift)
                f32x16 st[2];
                __builtin_amdgcn_s_setprio(1);
#pragma unroll
                for (int jt = 0; jt < 2; ++jt) {
                    if (jt >= njt) continue;
                    f32x16 s;
#pragma unroll
                    for (int r = 0; r < 16; ++r) s[r] = -16.f;
#pragma unroll
                    for (int k16 = 0; k16 < 4; ++k16) {
                        const int jrow = p2 * 64 + jt * 32 + qn;
                        const short8 kf = *(const short8*)
                            &Ks[buf][jrow * 64 + (((k16 * 2 + h) ^ (jrow & 7)) << 3)];
                        s = __builtin_amdgcn_mfma_f32_32x32x16_bf16(
                            kf, qf[k16], s, 0, 0, 0);
                    }
                    st[jt] = s;
                }
                __builtin_amdgcn_s_setprio(0);

                // causal mask (only needed near the diagonal)
                const int qg = q0w + qn;
#pragma unroll
                for (int jt = 0; jt < 2; ++jt) {
                    if (jt >= njt) continue;
                    const bool needMask = (jb + jt * 32 + 31) > q0w;
                    if (needMask) {
#pragma unroll
                        for (int r = 0; r < 16; ++r) {
                            const int jg = jb + jt * 32 +
                                           (r & 3) + 8 * (r >> 2) + 4 * h;
                            if (jg > qg) st[jt][r] = -1e30f;
                        }
                    }
                }

                // p = exp2(st) directly; 4-way ILP sum tree
                float ls = 0.f;
#pragma unroll
                for (int jt = 0; jt < 2; ++jt) {
                    if (jt >= njt) continue;
                    float s0 = 0.f, s1 = 0.f, s2 = 0.f, s3 = 0.f;
#pragma unroll
                    for (int r = 0; r < 16; r += 4) {
                        float p0 = exp2f(st[jt][r]);
                        float p1 = exp2f(st[jt][r + 1]);
                        float p2e = exp2f(st[jt][r + 2]);
                        float p3 = exp2f(st[jt][r + 3]);
                        st[jt][r] = p0; st[jt][r + 1] = p1;
                        st[jt][r + 2] = p2e; st[jt][r + 3] = p3;
                        s0 += p0; s1 += p1; s2 += p2e; s3 += p3;
                    }
                    ls += (s0 + s1) + (s2 + s3);
                }
                ls += __shfl_xor(ls, 32);
                l_run += ls;

                // PV: O^T += V^T P^T, P straight from st regs
                __builtin_amdgcn_s_setprio(1);
#pragma unroll
                for (int jt = 0; jt < 2; ++jt) {
                    if (jt >= njt) continue;
#pragma unroll
                    for (int g = 0; g < 4; ++g) {
                        bf16x4 pk;
#pragma unroll
                        for (int e = 0; e < 4; ++e)
                            pk[e] = (short)f2bf(st[jt][g * 4 + e]);
#pragma unroll
                        for (int dt = 0; dt < 2; ++dt) {
                            const int drow = dt * 32 + qn;
                            const int ch = (p2 * 8 + jt * 4 + g) ^ (drow & 15);
                            const bf16x4 vf = *(const bf16x4*)
                                &Vs[buf][drow * 128 + (ch << 3) + h * 4];
                            o_acc[dt] = __builtin_amdgcn_mfma_f32_32x32x8bf16_1k(
                                vf, pk, o_acc[dt], 0, 0, 0);
                        }
                    }
                }
                __builtin_amdgcn_s_setprio(0);
            }
        }

        // write y [B,T,D] bf16: t = q0w + qn, d = dt*32 + 8g + 4h + e
        const float inv = 1.f / l_run;
        const int t = q0 + w * 32 + qn;
        u16* yrow = y + ((size_t)(bb * T_SEQ + t)) * DMODEL + hh * HD;
#pragma unroll
        for (int dt = 0; dt < 2; ++dt)
#pragma unroll
            for (int g = 0; g < 4; ++g) {
                bf16x4 ov;
#pragma unroll
                for (int e = 0; e < 4; ++e)
                    ov[e] = (short)f2bf(o_acc[dt][g * 4 + e] * inv);
                *(bf16x4*)&yrow[dt * 32 + g * 8 + h * 4] = ov;
            }
    }
}

extern "C" void kernel_launch(void* const* d_in, const int* in_sizes, int n_in,
                              void* d_out, int out_size, void* d_ws, size_t ws_size,
                              hipStream_t stream) {
    const float* x      = (const float*)d_in[0];
    const float* w_qkv  = (const float*)d_in[1];
    const float* b_qkv  = (const float*)d_in[2];
    const float* w_proj = (const float*)d_in[3];
    const float* b_proj = (const float*)d_in[4];
    float* out = (float*)d_out;

    u16* xb  = (u16*)d_ws;
    u16* wqT = xb + 8388608;
    u16* wpT = wqT + 3145728;
    u16* qkv = wpT + 1048576;           // q | k | vT
    u16* yb  = qkv + 3 * QKV_ELEMS;

    prep_kernel<<<2304, 256, 0, stream>>>((const float4*)x, xb,
                                          w_qkv, wqT, w_proj, wpT);
    gemm_kernel<0><<<dim3(24, 64), 256, 0, stream>>>(xb, wqT, b_qkv, (void*)qkv);
    attn_kernel<<<dim3(512), 256, 0, stream>>>(
        qkv, qkv + QKV_ELEMS, qkv + 2 * QKV_ELEMS, yb);
    gemm_kernel<1><<<dim3(8, 64), 256, 0, stream>>>(yb, wpT, b_proj, (void*)out);
}

// Round 10
// 272.308 us; speedup vs baseline: 1.1372x; 1.1372x over previous
//
#include <hip/hip_runtime.h>
#include <hip/hip_bf16.h>

typedef unsigned short u16;
typedef short short8 __attribute__((ext_vector_type(8)));
typedef short bf16x4 __attribute__((ext_vector_type(4)));
typedef float f32x4 __attribute__((ext_vector_type(4)));
typedef float f32x16 __attribute__((ext_vector_type(16)));

#define B_SZ 4
#define T_SEQ 2048
#define DMODEL 1024
#define NH 16
#define HD 64
#define QKV_ELEMS 8388608ull  // B*NH*T*HD
#define QSCALE (0.125f * 1.44269504f)   // HD^-0.5 * log2(e), folded into Q

__device__ __forceinline__ u16 f2bf(float f) {
    __hip_bfloat16 h = __float2bfloat16(f);
    return __builtin_bit_cast(u16, h);
}

// async global->LDS, 16B/lane; lane i lands at base + 16*i (wave-uniform base).
__device__ __forceinline__ void gload16(const void* g, void* l) {
    __builtin_amdgcn_global_load_lds(
        (const __attribute__((address_space(1))) unsigned int*)g,
        (__attribute__((address_space(3))) unsigned int*)l, 16, 0, 0);
}

// ---------------------------------------------------------------------------
// Fused prep (R8, verified -29 us vs serial launches): one launch replaces
// cast_x + 2 tcasts. Blocks [0,2048): cast x -> bf16, 4x float4/thread.
// Blocks [2048,2240): transpose-cast w_qkv. [2240,2304): w_proj.
// ---------------------------------------------------------------------------
#define NCX 2048
__global__ __launch_bounds__(256) void prep_kernel(
    const float4* __restrict__ x, u16* __restrict__ xb,
    const float* __restrict__ w_qkv, u16* __restrict__ wqT,
    const float* __restrict__ w_proj, u16* __restrict__ wpT)
{
    const int b = blockIdx.x;
    if (b < NCX) {
        int i = b * 256 + threadIdx.x;
#pragma unroll
        for (int rep = 0; rep < 4; ++rep, i += NCX * 256) {
            const float4 v = x[i];
            union { u16 u[4]; uint2 d; } p;
            p.u[0] = f2bf(v.x); p.u[1] = f2bf(v.y);
            p.u[2] = f2bf(v.z); p.u[3] = f2bf(v.w);
            *(uint2*)(xb + (size_t)i * 4) = p.d;
        }
    } else if (b < NCX + 192) {
        const int bb2 = b - NCX;
        const int n = (bb2 % 12) * 256 + threadIdx.x;
        const int k0 = (bb2 / 12) * 64;
        for (int kk = 0; kk < 64; kk += 8) {
            short8 o;
#pragma unroll
            for (int e = 0; e < 8; ++e)
                o[e] = (short)f2bf(w_qkv[(size_t)(k0 + kk + e) * 3072 + n]);
            *(short8*)&wqT[(size_t)n * 1024 + k0 + kk] = o;
        }
    } else {
        const int bb2 = b - NCX - 192;
        const int n = (bb2 % 4) * 256 + threadIdx.x;
        const int k0 = (bb2 / 4) * 64;
        for (int kk = 0; kk < 64; kk += 8) {
            short8 o;
#pragma unroll
            for (int e = 0; e < 8; ++e)
                o[e] = (short)f2bf(w_proj[(size_t)(k0 + kk + e) * 1024 + n]);
            *(short8*)&wpT[(size_t)n * 1024 + k0 + kk] = o;
        }
    }
}

// ---------------------------------------------------------------------------
// bf16 MFMA GEMM 128x128xBK64 — EXACT R3/R8 state (verified; splits/swaps
// regressed). EPI=0: scatter q (pre-scaled) / k into [B,H,T,HD] and V
// TRANSPOSED into [B,H,HD,T]. EPI=1: fp32 out.
// ---------------------------------------------------------------------------
template <int EPI>
__global__ __launch_bounds__(256) void gemm_kernel(
    const u16* __restrict__ A, const u16* __restrict__ Bt,
    const float* __restrict__ bias, void* __restrict__ outp)
{
    __shared__ u16 As[128 * 64];
    __shared__ u16 Bs[128 * 64];
    const int tid = threadIdx.x;
    const int l = tid & 63;
    const int w = tid >> 6;
    const int wm = w >> 1, wn = w & 1;
    const int m0 = blockIdx.y * 128, n0 = blockIdx.x * 128;
    const int srow = l >> 3;
    const int sch  = (l & 7) ^ srow;
    const int fr = l & 15, fq = l >> 4;

    f32x4 acc[4][4] = {};

    for (int k0 = 0; k0 < 1024; k0 += 64) {
        __syncthreads();
#pragma unroll
        for (int ii = 0; ii < 4; ++ii) {
            const int row = w * 32 + ii * 8;
            gload16(&A[(size_t)(m0 + row + srow) * 1024 + k0 + sch * 8], &As[row * 64]);
            gload16(&Bt[(size_t)(n0 + row + srow) * 1024 + k0 + sch * 8], &Bs[row * 64]);
        }
        __syncthreads();
#pragma unroll
        for (int ks = 0; ks < 2; ++ks) {
            short8 af[4], bf[4];
#pragma unroll
            for (int t = 0; t < 4; ++t) {
                const int ar = wm * 64 + t * 16 + fr;
                af[t] = *(const short8*)&As[ar * 64 + (((ks * 4 + fq) ^ (l & 7)) << 3)];
                const int br = wn * 64 + t * 16 + fr;
                bf[t] = *(const short8*)&Bs[br * 64 + (((ks * 4 + fq) ^ (l & 7)) << 3)];
            }
#pragma unroll
            for (int mt = 0; mt < 4; ++mt)
#pragma unroll
                for (int nt = 0; nt < 4; ++nt)
                    acc[mt][nt] = __builtin_amdgcn_mfma_f32_16x16x32_bf16(
                        af[mt], bf[nt], acc[mt][nt], 0, 0, 0);
        }
    }

    if (EPI == 0) {
        u16* qkv = (u16*)outp;
#pragma unroll
        for (int nt = 0; nt < 4; ++nt) {
            const int n = n0 + wn * 64 + nt * 16 + fr;
            const float bs = bias[n];
            const int which = n >> 10, hh = (n >> 6) & 15, d = n & 63;
            if (which == 2) {
                // V transposed: [b][h][d][t]; lane's 4 r-values are t-contiguous
                u16* dst = qkv + 2 * QKV_ELEMS;
#pragma unroll
                for (int mt = 0; mt < 4; ++mt) {
                    const int m = m0 + wm * 64 + mt * 16 + fq * 4;
                    const int bb = m >> 11, t = m & 2047;
                    bf16x4 ov;
#pragma unroll
                    for (int r = 0; r < 4; ++r) ov[r] = (short)f2bf(acc[mt][nt][r] + bs);
                    *(bf16x4*)&dst[(((size_t)(bb * NH + hh)) * HD + d) * T_SEQ + t] = ov;
                }
            } else {
                const float scl = (which == 0) ? QSCALE : 1.0f;
                u16* dst = qkv + (size_t)which * QKV_ELEMS + (size_t)hh * T_SEQ * HD + d;
#pragma unroll
                for (int mt = 0; mt < 4; ++mt)
#pragma unroll
                    for (int r = 0; r < 4; ++r) {
                        const int m = m0 + wm * 64 + mt * 16 + fq * 4 + r;
                        const int bb = m >> 11, t = m & 2047;
                        dst[(size_t)bb * (NH * T_SEQ * HD) + (size_t)t * HD] =
                            f2bf((acc[mt][nt][r] + bs) * scl);
                    }
            }
        }
    } else {
        float* C = (float*)outp;
#pragma unroll
        for (int nt = 0; nt < 4; ++nt) {
            const int n = n0 + wn * 64 + nt * 16 + fr;
            const float bs = bias[n];
#pragma unroll
            for (int mt = 0; mt < 4; ++mt)
#pragma unroll
                for (int r = 0; r < 4; ++r) {
                    const int m = m0 + wm * 64 + mt * 16 + fq * 4 + r;
                    C[(size_t)m * DMODEL + n] = acc[mt][nt][r] + bs;
                }
        }
    }
}

// ---------------------------------------------------------------------------
// MFMA flash attention — R8 memory structure (KVBLK=64, verified 100 µs /
// FETCH 24.7 MB; R9's KVBLK=128 regressed to 130 and is reverted), now with
// 8 WAVES per block split by j-subtile: waves 0-3 own q-rows (w&3)*32 and
// jt=0; waves 4-7 duplicate the q-rows and own jt=1. The gload sequence,
// tile order, and LDS layout are IDENTICAL to R8 (the invariant R4/R6 broke)
// — only intra-block work division changes: 2 blocks/CU x 8 waves = 4
// waves/SIMD (was 2), and per-wave softmax VALU halves. Fixed-shift softmax
// (no running max) makes the jt0+jt1 combine a pure sum, done once per
// q-tile through dead LDS. 512 blocks, pair-sequential (qi, 15-qi), 8 heads
// per XCD L2 pinning, setprio on MFMA clusters — all unchanged.
// ---------------------------------------------------------------------------
__global__ __launch_bounds__(512, 4) void attn_kernel(
    const u16* __restrict__ q, const u16* __restrict__ k,
    const u16* __restrict__ vT, u16* __restrict__ y)
{
    __shared__ u16 Ks[2][64 * 64];   // 16 KB [j][d]; also Q staging (128 rows)
    __shared__ u16 Vs[2][64 * 64];   // 16 KB [d][t]
    __shared__ float Lx[256];        // l-partial exchange (1 KB)

    int flat = blockIdx.x;
    flat = (flat & 7) * 64 + (flat >> 3);
    const int qip = flat & 7;
    const int hh = (flat >> 3) & 15;
    const int bb = flat >> 7;

    const size_t hbase = ((size_t)(bb * NH + hh)) * T_SEQ * HD;
    const u16* qb = q + hbase;
    const u16* kb = k + hbase;
    const u16* vTb = vT + hbase;     // [d][t]

    const int tid = threadIdx.x;
    const int l = tid & 63;
    const int wid = tid >> 6;        // 0..7
    const int w4 = wid & 3;          // q-row group (32 rows)
    const int jtw = wid >> 2;        // j-subtile this wave owns (0 or 1)
    const int qn = l & 31;           // q within wave tile
    const int h = l >> 5;            // half-wave
    const int srow = l >> 3;
    const int sch = (l & 7) ^ srow;

    u16* Qstage = &Ks[0][0];         // 16 KB spanning both Ks buffers

    for (int pp = 0; pp < 2; ++pp) {
        const int qi = pp ? (15 - qip) : qip;
        const int q0 = qi * 128;

        __syncthreads();   // previous tile fully done with LDS

        // stage Q (128 rows -> Ks area): wave wid stages rows [wid*16,+16)
        {
            const int row = wid * 16, row2 = wid * 16 + 8;
            gload16(&qb[(size_t)(q0 + row + srow) * HD + sch * 8], &Qstage[row * 64]);
            gload16(&qb[(size_t)(q0 + row2 + srow) * HD + sch * 8], &Qstage[row2 * 64]);
        }
        // V tile 0: wave wid stages rows [wid*8,+8)
        {
            const int row = wid * 8;
            gload16(&vTb[(size_t)(row + srow) * T_SEQ + sch * 8], &Vs[0][row * 64]);
        }
        __syncthreads();   // Q + V0 landed

        // hoist Q fragments (B-operand 32x32x16: n=q=qn, k=k16*16+h*8+e)
        short8 qf[4];
        {
            const int qrow = w4 * 32 + qn;
#pragma unroll
            for (int k16 = 0; k16 < 4; ++k16)
                qf[k16] = *(const short8*)
                    &Qstage[qrow * 64 + (((k16 * 2 + h) ^ (qrow & 7)) << 3)];
        }
        __syncthreads();   // all waves done reading Q; Ks reusable

        // K tile 0: wave wid stages rows [wid*8,+8)
        {
            const int row = wid * 8;
            gload16(&kb[(size_t)(row + srow) * HD + sch * 8], &Ks[0][row * 64]);
        }

        const int q0w = q0 + w4 * 32;    // this wave's first q row
        float l_run = 0.f;
        f32x16 o_acc[2] = {};            // O^T partial (this jt half)

        const int nkt = 2 * (qi + 1);
        for (int kt = 0; kt < nkt; ++kt) {
            __syncthreads();   // drains prev gloads (incl. tile 0) + readers done
            if (kt + 1 < nkt) {
                const int nb = (kt + 1) & 1;
                const int jj = (kt + 1) * 64;
                const int row = wid * 8;
                gload16(&kb[(size_t)(jj + row + srow) * HD + sch * 8],
                        &Ks[nb][row * 64]);
                gload16(&vTb[(size_t)(row + srow) * T_SEQ + jj + sch * 8],
                        &Vs[nb][row * 64]);
            }
            const int buf = kt & 1;
            const int jb = kt * 64 + jtw * 32;   // this wave's 32-j subtile

            if (jb > q0w + 31) continue;         // subtile masked for this wave

            // S^T = K Q^T, accumulator pre-shifted by -16 (softmax shift)
            f32x16 st;
            __builtin_amdgcn_s_setprio(1);
            {
                f32x16 s;
#pragma unroll
                for (int r = 0; r < 16; ++r) s[r] = -16.f;
#pragma unroll
                for (int k16 = 0; k16 < 4; ++k16) {
                    const int jrow = jtw * 32 + qn;
                    const short8 kf = *(const short8*)
                        &Ks[buf][jrow * 64 + (((k16 * 2 + h) ^ (jrow & 7)) << 3)];
                    s = __builtin_amdgcn_mfma_f32_32x32x16_bf16(kf, qf[k16], s, 0, 0, 0);
                }
                st = s;
            }
            __builtin_amdgcn_s_setprio(0);

            // causal mask (only needed near the diagonal)
            const int qg = q0w + qn;
            if (jb + 31 > q0w) {
#pragma unroll
                for (int r = 0; r < 16; ++r) {
                    const int jg = jb + (r & 3) + 8 * (r >> 2) + 4 * h;
                    if (jg > qg) st[r] = -1e30f;
                }
            }

            // p = exp2(st) directly; 4-way ILP sum tree
            float s0 = 0.f, s1 = 0.f, s2 = 0.f, s3 = 0.f;
#pragma unroll
            for (int r = 0; r < 16; r += 4) {
                float p0 = exp2f(st[r]);
                float p1 = exp2f(st[r + 1]);
                float p2 = exp2f(st[r + 2]);
                float p3 = exp2f(st[r + 3]);
                st[r] = p0; st[r + 1] = p1; st[r + 2] = p2; st[r + 3] = p3;
                s0 += p0; s1 += p1; s2 += p2; s3 += p3;
            }
            float ls = (s0 + s1) + (s2 + s3);
            ls += __shfl_xor(ls, 32);
            l_run += ls;

            // PV: O^T += V^T P^T, P straight from st regs
            __builtin_amdgcn_s_setprio(1);
#pragma unroll
            for (int g = 0; g < 4; ++g) {
                bf16x4 pk;
#pragma unroll
                for (int e = 0; e < 4; ++e) pk[e] = (short)f2bf(st[g * 4 + e]);
#pragma unroll
                for (int dt = 0; dt < 2; ++dt) {
                    const int drow = dt * 32 + qn;
                    const bf16x4 vf = *(const bf16x4*)
                        &Vs[buf][drow * 64 +
                                 (((jtw * 4 + g) ^ (drow & 7)) << 3) + h * 4];
                    o_acc[dt] = __builtin_amdgcn_mfma_f32_32x32x8bf16_1k(
                        vf, pk, o_acc[dt], 0, 0, 0);
                }
            }
            __builtin_amdgcn_s_setprio(0);
        }

        // ---- combine jt0+jt1 partials (pure sum: fixed-shift softmax) ----
        __syncthreads();                 // all compute done; Ks/Vs dead
        const int ridx = w4 * 64 + l;    // 0..255; same for waves wid, wid+4
        if (jtw == 1) {
#pragma unroll
            for (int dt = 0; dt < 2; ++dt) {
                float* xo = dt ? (float*)&Vs[0][0] : (float*)&Ks[0][0];
#pragma unroll
                for (int g = 0; g < 4; ++g) {
                    f32x4 v;
#pragma unroll
                    for (int e = 0; e < 4; ++e) v[e] = o_acc[dt][g * 4 + e];
                    *(f32x4*)&xo[ridx * 16 + ((g ^ (ridx & 3)) << 2)] = v;
                }
            }
            Lx[ridx] = l_run;
        }
        __syncthreads();                 // partials visible
        if (jtw == 0) {
#pragma unroll
            for (int dt = 0; dt < 2; ++dt) {
                const float* xo = dt ? (const float*)&Vs[0][0]
                                     : (const float*)&Ks[0][0];
#pragma unroll
                for (int g = 0; g < 4; ++g) {
                    const f32x4 v =
                        *(const f32x4*)&xo[ridx * 16 + ((g ^ (ridx & 3)) << 2)];
#pragma unroll
                    for (int e = 0; e < 4; ++e) o_acc[dt][g * 4 + e] += v[e];
                }
            }
            const float lt = l_run + Lx[ridx];

            // write y [B,T,D] bf16: t = q0w + qn, d = dt*32 + 8g + 4h + e
            const float inv = 1.f / lt;
            const int t = q0 + w4 * 32 + qn;
            u16* yrow = y + ((size_t)(bb * T_SEQ + t)) * DMODEL + hh * HD;
#pragma unroll
            for (int dt = 0; dt < 2; ++dt)
#pragma unroll
                for (int g = 0; g < 4; ++g) {
                    bf16x4 ov;
#pragma unroll
                    for (int e = 0; e < 4; ++e)
                        ov[e] = (short)f2bf(o_acc[dt][g * 4 + e] * inv);
                    *(bf16x4*)&yrow[dt * 32 + g * 8 + h * 4] = ov;
                }
        }
    }
}

extern "C" void kernel_launch(void* const* d_in, const int* in_sizes, int n_in,
                              void* d_out, int out_size, void* d_ws, size_t ws_size,
                              hipStream_t stream) {
    const float* x      = (const float*)d_in[0];
    const float* w_qkv  = (const float*)d_in[1];
    const float* b_qkv  = (const float*)d_in[2];
    const float* w_proj = (const float*)d_in[3];
    const float* b_proj = (const float*)d_in[4];
    float* out = (float*)d_out;

    u16* xb  = (u16*)d_ws;
    u16* wqT = xb + 8388608;
    u16* wpT = wqT + 3145728;
    u16* qkv = wpT + 1048576;           // q | k | vT
    u16* yb  = qkv + 3 * QKV_ELEMS;

    prep_kernel<<<2304, 256, 0, stream>>>((const float4*)x, xb,
                                          w_qkv, wqT, w_proj, wpT);
    gemm_kernel<0><<<dim3(24, 64), 256, 0, stream>>>(xb, wqT, b_qkv, (void*)qkv);
    attn_kernel<<<dim3(512), 512, 0, stream>>>(
        qkv, qkv + QKV_ELEMS, qkv + 2 * QKV_ELEMS, yb);
    gemm_kernel<1><<<dim3(8, 64), 256, 0, stream>>>(yb, wpT, b_proj, (void*)out);
}